// Round 4
// baseline (213.137 us; speedup 1.0000x reference)
//
#include <hip/hip_runtime.h>
#include <cstdint>
#include <cstddef>

#define A_N 33600
#define G_N 256
#define C_N 80
#define TOPK 10
#define CAP 2048

// Inputs are FLOAT32 (reference setup_inputs dtypes); gt_labels int32; output flat f32.

// K1: total_neg[a] = sum_c softplus(scores[a,c]) (f64 accum -> f32);
//     sT[c*A+a] = scores[a,c] (f32 transpose); assigned[a] = -1
__global__ __launch_bounds__(256) void k1_prep(const float* __restrict__ scores,
                                               float* __restrict__ total_neg,
                                               float* __restrict__ sT,
                                               int* __restrict__ assigned) {
    __shared__ float tile[128][81];  // pad 80->81
    const int a0 = blockIdx.x * 128;
    const int tid = threadIdx.x;
    for (int idx = tid; idx < 128 * C_N; idx += 256) {
        int gidx = a0 * C_N + idx;
        tile[idx / C_N][idx % C_N] = (gidx < A_N * C_N) ? scores[gidx] : 0.f;
    }
    __syncthreads();
    for (int idx = tid; idx < C_N * 128; idx += 256) {
        int c = idx >> 7, j = idx & 127;
        int a = a0 + j;
        if (a < A_N) sT[(size_t)c * A_N + a] = tile[j][c];
    }
    if (tid < 128) {
        int a = a0 + tid;
        if (a < A_N) {
            double s = 0.0;
            for (int c = 0; c < C_N; ++c) {
                float x = tile[tid][c];
                s += (double)(fmaxf(x, 0.f) + log1pf(expf(-fabsf(x))));
            }
            total_neg[a] = (float)s;
            assigned[a] = -1;
        }
    }
}

// K2: one block per GT. f32 cost (matches np f32 ref); inside-list compaction;
// dyn_k rounds of argmin with lowest-index tie-break; scatter atomicMax.
// Empty-inside GT: f32 cost+1e10 collapses ALL entries to one value (cost<512,
// ulp(1e10)=1024) -> top_k tie-break -> anchor 0.
__global__ __launch_bounds__(256) void k2_assign(const float* __restrict__ anchor_pts,
                                                 const float* __restrict__ pred_boxes,
                                                 const float* __restrict__ total_neg,
                                                 const float* __restrict__ sT,
                                                 const int* __restrict__ gt_labels,
                                                 const float* __restrict__ gt_boxes,
                                                 int* __restrict__ assigned) {
    __shared__ float lcost[CAP];
    __shared__ int   lidx[CAP];
    __shared__ float rval[256];
    __shared__ int   ridx[256];
    __shared__ float wv_s;
    __shared__ int   wi_s;
    __shared__ int lcnt, lpos;
    const int g = blockIdx.x;
    const int tid = threadIdx.x;
    if (tid == 0) { lcnt = 0; lpos = 0; }
    __syncthreads();

    const float4 gb = *(const float4*)(gt_boxes + 4 * g);
    const float gx1 = gb.x, gy1 = gb.y, gx2 = gb.z, gy2 = gb.w;
    const int lbl = gt_labels[g];
    const float area_g = (gx2 - gx1) * (gy2 - gy1);
    const float* __restrict__ srow = sT + (size_t)lbl * A_N;

    // in_center (cx +- 2.5w) strictly contains in_gt (cx +- 0.5w) -> inside == in_gt
    for (int a = tid; a < A_N; a += 256) {
        float2 ap = *(const float2*)(anchor_pts + 2 * a);
        float4 pb = *(const float4*)(pred_boxes + 4 * a);
        bool inside = (ap.x >= gx1) && (ap.x <= gx2) && (ap.y >= gy1) && (ap.y <= gy2);
        if (inside) {
            float ltx = fmaxf(pb.x, gx1), lty = fmaxf(pb.y, gy1);
            float rbx = fminf(pb.z, gx2), rby = fminf(pb.w, gy2);
            float wx = fmaxf(rbx - ltx, 0.f), wy = fmaxf(rby - lty, 0.f);
            float ov = wx * wy;
            float area_p = (pb.z - pb.x) * (pb.w - pb.y);
            float iou = ov / (area_p + area_g - ov + 1e-6f);
            float cost = (total_neg[a] - srow[a]) + 3.0f * (-logf(fmaxf(iou, 1e-7f)));
            int i = atomicAdd(&lcnt, 1);
            if (i < CAP) { lcost[i] = cost; lidx[i] = a; }
            if (ov > 0.f) atomicAdd(&lpos, 1);
        }
    }
    __syncthreads();
    const int cnt = min(lcnt, CAP);
    const int dynk = min(max(lpos, 1), TOPK);

    if (cnt == 0) {
        // all costs collapse to f32(1e10-ish) -> ref top_k picks anchors 0..9, rank0 -> anchor 0
        if (tid == 0) atomicMax(&assigned[0], g);
        return;
    }
    // dynk <= cnt guaranteed (lpos <= lcnt; lpos==0 -> dynk==1 <= cnt)
    for (int r = 0; r < dynk; ++r) {
        float bv = 3.4e38f; int bi = 0x7FFFFFFF;
        for (int i = tid; i < cnt; i += 256) {
            float v = lcost[i]; int ai = lidx[i];
            if (v < bv || (v == bv && ai < bi)) { bv = v; bi = ai; }
        }
        rval[tid] = bv; ridx[tid] = bi;
        __syncthreads();
        for (int s = 128; s; s >>= 1) {
            if (tid < s) {
                float v = rval[tid + s]; int i = ridx[tid + s];
                if (v < rval[tid] || (v == rval[tid] && i < ridx[tid])) { rval[tid] = v; ridx[tid] = i; }
            }
            __syncthreads();
        }
        if (tid == 0) {
            wv_s = rval[0]; wi_s = ridx[0];
            atomicMax(&assigned[ridx[0]], g);
        }
        __syncthreads();
        float wv = wv_s; int wi = wi_s;
        for (int i = tid; i < cnt; i += 256) {
            if (lcost[i] == wv && lidx[i] == wi) lcost[i] = 3.4e38f;  // unique per anchor
        }
        __syncthreads();
    }
}

// K3: out (f32): labels[A] | bboxes[A*4] | scores[A*81]. Zeroes its own score rows.
__global__ __launch_bounds__(256) void k3_final(const float* __restrict__ pred_boxes,
                                                const int* __restrict__ gt_labels,
                                                const float* __restrict__ gt_boxes,
                                                const int* __restrict__ assigned,
                                                float* __restrict__ out) {
    const int a0 = blockIdx.x * 256;
    const int tid = threadIdx.x;
    const int hi = min(a0 + 256, A_N);
    float* __restrict__ sc_out = out + 5 * A_N;
    const int n = (hi - a0) * 81;
    for (int i = tid; i < n; i += 256) sc_out[(size_t)a0 * 81 + i] = 0.f;
    __syncthreads();
    int a = a0 + tid;
    if (a >= A_N) return;
    int g = assigned[a];
    float* lbl_out = out;
    float* box_out = out + A_N;
    if (g >= 0) {
        int lbl = gt_labels[g];
        lbl_out[a] = (float)lbl;
        float4 gb = *(const float4*)(gt_boxes + 4 * g);
        *(float4*)(box_out + 4 * a) = gb;  // exact copy
        float4 pb = *(const float4*)(pred_boxes + 4 * a);
        float ltx = fmaxf(pb.x, gb.x), lty = fmaxf(pb.y, gb.y);
        float rbx = fminf(pb.z, gb.z), rby = fminf(pb.w, gb.w);
        float wx = fmaxf(rbx - ltx, 0.f), wy = fmaxf(rby - lty, 0.f);
        float ov = wx * wy;
        float area_p = (pb.z - pb.x) * (pb.w - pb.y);
        float area_g = (gb.z - gb.x) * (gb.w - gb.y);
        float iou = ov / (area_p + area_g - ov + 1e-6f);
        sc_out[(size_t)a * 81 + lbl] = iou;
    } else {
        lbl_out[a] = 80.0f;
        float4 z; z.x = 0.f; z.y = 0.f; z.z = 0.f; z.w = 0.f;
        *(float4*)(box_out + 4 * a) = z;
    }
}

extern "C" void kernel_launch(void* const* d_in, const int* in_sizes, int n_in,
                              void* d_out, int out_size, void* d_ws, size_t ws_size,
                              hipStream_t stream) {
    (void)in_sizes; (void)n_in; (void)out_size; (void)ws_size;
    const float* pred_scores = (const float*)d_in[0];
    const float* pred_bboxes = (const float*)d_in[1];
    const float* anchor_pts  = (const float*)d_in[2];
    const int*   gt_labels   = (const int*)d_in[3];
    const float* gt_boxes    = (const float*)d_in[4];
    float* out = (float*)d_out;

    char* ws = (char*)d_ws;
    float* total_neg = (float*)ws;                            // A_N f32
    int*   assigned  = (int*)(ws + (size_t)A_N * 4);          // A_N i32
    float* sT        = (float*)(ws + (size_t)A_N * 8);        // C_N*A_N f32 (~10.75 MB)

    k1_prep<<<(A_N + 127) / 128, 256, 0, stream>>>(pred_scores, total_neg, sT, assigned);
    k2_assign<<<G_N, 256, 0, stream>>>(anchor_pts, pred_bboxes, total_neg, sT,
                                       gt_labels, gt_boxes, assigned);
    k3_final<<<(A_N + 255) / 256, 256, 0, stream>>>(pred_bboxes, gt_labels, gt_boxes,
                                                    assigned, out);
}

// Round 5
// 161.351 us; speedup vs baseline: 1.3210x; 1.3210x over previous
//
#include <hip/hip_runtime.h>
#include <cstdint>
#include <cstddef>

#define A_N 33600
#define G_N 256
#define C_N 80
#define TOPK 10
#define CAP 2048
#define GW 40           // 40x40 grid of 32-px cells
#define NC (GW * GW)    // 1600 cells

// Inputs: float32 (pred_scores, pred_bboxes, anchor_points, gt_bboxes), int32 gt_labels.
// Output (float32 flat): labels[A] | bboxes[A*4] | scores[A*81].

// K1: total_neg[a] = sum_c softplus(scores[a,c]) (f32 terms, f64 accum — matched absmax 0.0);
//     sT[c*A+a] transpose; assigned[a]=-1; fused histogram of anchor cells.
__global__ __launch_bounds__(256) void k1_prep(const float* __restrict__ scores,
                                               const float* __restrict__ anchor_pts,
                                               float* __restrict__ total_neg,
                                               float* __restrict__ sT,
                                               int* __restrict__ assigned,
                                               int* __restrict__ cellcnt) {
    __shared__ float tile[128][81];  // pad 80->81
    const int a0 = blockIdx.x * 128;
    const int tid = threadIdx.x;
    for (int idx = tid; idx < 128 * C_N; idx += 256) {
        int gidx = a0 * C_N + idx;
        tile[idx / C_N][idx % C_N] = (gidx < A_N * C_N) ? scores[gidx] : 0.f;
    }
    if (tid < 128) {
        int a = a0 + tid;
        if (a < A_N) {
            float2 ap = *(const float2*)(anchor_pts + 2 * a);
            int cx = min(GW - 1, (int)(ap.x * (1.f / 32.f)));  // ap in [0,1280]
            int cy = min(GW - 1, (int)(ap.y * (1.f / 32.f)));
            atomicAdd(&cellcnt[cy * GW + cx], 1);
            assigned[a] = -1;
        }
    }
    __syncthreads();
    for (int idx = tid; idx < C_N * 128; idx += 256) {
        int c = idx >> 7, j = idx & 127;
        int a = a0 + j;
        if (a < A_N) sT[(size_t)c * A_N + a] = tile[j][c];
    }
    if (tid < 128) {
        int a = a0 + tid;
        if (a < A_N) {
            double s = 0.0;
            for (int c = 0; c < C_N; ++c) {
                float x = tile[tid][c];
                s += (double)(fmaxf(x, 0.f) + log1pf(expf(-fabsf(x))));
            }
            total_neg[a] = (float)s;
        }
    }
}

// K0b: exclusive scan of cellcnt[1600] -> offsets[1601]; single block.
__global__ __launch_bounds__(256) void k0_scan(const int* __restrict__ cellcnt,
                                               int* __restrict__ offsets) {
    __shared__ int part[256];
    const int tid = threadIdx.x;
    const int CH = 7;  // 256*7 = 1792 >= 1601
    int base = tid * CH;
    int loc[CH];
    int s = 0;
    for (int i = 0; i < CH; ++i) {
        int c = base + i;
        int v = (c < NC) ? cellcnt[c] : 0;
        loc[i] = s;
        s += v;
    }
    part[tid] = s;
    __syncthreads();
    for (int off = 1; off < 256; off <<= 1) {
        int v = (tid >= off) ? part[tid - off] : 0;
        __syncthreads();
        part[tid] += v;
        __syncthreads();
    }
    int pre = (tid == 0) ? 0 : part[tid - 1];
    for (int i = 0; i < CH; ++i) {
        int c = base + i;
        if (c <= NC) offsets[c] = pre + loc[i];
    }
}

// K0c: counting-sort scatter of per-anchor data (xy, box, total_neg, orig idx).
__global__ __launch_bounds__(256) void k0_scatter(const float* __restrict__ anchor_pts,
                                                  const float* __restrict__ pred_boxes,
                                                  const float* __restrict__ total_neg,
                                                  const int* __restrict__ offsets,
                                                  int* __restrict__ fill,
                                                  float2* __restrict__ sxy,
                                                  float4* __restrict__ sbox,
                                                  float* __restrict__ stn,
                                                  int* __restrict__ sidx) {
    int a = blockIdx.x * 256 + threadIdx.x;
    if (a >= A_N) return;
    float2 ap = *(const float2*)(anchor_pts + 2 * a);
    int cx = min(GW - 1, (int)(ap.x * (1.f / 32.f)));
    int cy = min(GW - 1, (int)(ap.y * (1.f / 32.f)));
    int cell = cy * GW + cx;
    int pos = offsets[cell] + atomicAdd(&fill[cell], 1);
    sxy[pos] = ap;
    sbox[pos] = *(const float4*)(pred_boxes + 4 * a);
    stn[pos] = total_neg[a];
    sidx[pos] = a;
}

// K2: one block per GT. Scan only this GT's cell rows (contiguous ranges).
// Winner keyed on (exact f32 cost, orig anchor idx) -> order-independent & matches np stable top_k.
__global__ __launch_bounds__(256) void k2_assign(const float2* __restrict__ sxy,
                                                 const float4* __restrict__ sbox,
                                                 const float* __restrict__ stn,
                                                 const int* __restrict__ sidx,
                                                 const float* __restrict__ sT,
                                                 const int* __restrict__ gt_labels,
                                                 const float* __restrict__ gt_boxes,
                                                 const int* __restrict__ offsets,
                                                 int* __restrict__ assigned) {
    __shared__ float lcost[CAP];
    __shared__ int   lidx[CAP];
    __shared__ float rv[4];
    __shared__ int   ri[4];
    __shared__ float wv_s;
    __shared__ int   wi_s;
    __shared__ int lcnt, lpos;
    const int g = blockIdx.x;
    const int tid = threadIdx.x;
    if (tid == 0) { lcnt = 0; lpos = 0; }
    __syncthreads();

    const float4 gb = *(const float4*)(gt_boxes + 4 * g);
    const int lbl = gt_labels[g];
    const float area_g = (gb.z - gb.x) * (gb.w - gb.y);
    const float* __restrict__ srow = sT + (size_t)lbl * A_N;

    int cx0 = max(0, (int)floorf(gb.x * (1.f / 32.f)));
    int cx1 = min(GW - 1, (int)floorf(gb.z * (1.f / 32.f)));
    int cy0 = max(0, (int)floorf(gb.y * (1.f / 32.f)));
    int cy1 = min(GW - 1, (int)floorf(gb.w * (1.f / 32.f)));

    for (int cy = cy0; cy <= cy1; ++cy) {
        int lo = offsets[cy * GW + cx0];
        int hi = offsets[cy * GW + cx1 + 1];
        for (int i = lo + tid; i < hi; i += 256) {
            float2 ap = sxy[i];
            if (ap.x >= gb.x && ap.x <= gb.z && ap.y >= gb.y && ap.y <= gb.w) {
                float4 pb = sbox[i];
                float ltx = fmaxf(pb.x, gb.x), lty = fmaxf(pb.y, gb.y);
                float rbx = fminf(pb.z, gb.z), rby = fminf(pb.w, gb.w);
                float wx = fmaxf(rbx - ltx, 0.f), wy = fmaxf(rby - lty, 0.f);
                float ov = wx * wy;
                float area_p = (pb.z - pb.x) * (pb.w - pb.y);
                float iou = ov / (area_p + area_g - ov + 1e-6f);
                int oa = sidx[i];
                float cost = (stn[i] - srow[oa]) + 3.0f * (-logf(fmaxf(iou, 1e-7f)));
                int k = atomicAdd(&lcnt, 1);
                if (k < CAP) { lcost[k] = cost; lidx[k] = oa; }
                if (ov > 0.f) atomicAdd(&lpos, 1);
            }
        }
    }
    __syncthreads();
    const int cnt = min(lcnt, CAP);
    const int dynk = min(max(lpos, 1), TOPK);

    if (cnt == 0) {
        // all-outside row: f32 cost+1e10 collapses (|cost|<512=ulp/2) -> ref top_k picks anchor 0
        if (tid == 0) atomicMax(&assigned[0], g);
        return;
    }
    for (int r = 0; r < dynk; ++r) {
        float bv = 3.4e38f; int bi = 0x7FFFFFFF;
        for (int i = tid; i < cnt; i += 256) {
            float v = lcost[i]; int ai = lidx[i];
            if (v < bv || (v == bv && ai < bi)) { bv = v; bi = ai; }
        }
        for (int off = 32; off; off >>= 1) {
            float vv = __shfl_down(bv, off);
            int ii = __shfl_down(bi, off);
            if (vv < bv || (vv == bv && ii < bi)) { bv = vv; bi = ii; }
        }
        if ((tid & 63) == 0) { rv[tid >> 6] = bv; ri[tid >> 6] = bi; }
        __syncthreads();
        if (tid == 0) {
            float v = rv[0]; int i = ri[0];
            for (int w = 1; w < 4; ++w)
                if (rv[w] < v || (rv[w] == v && ri[w] < i)) { v = rv[w]; i = ri[w]; }
            wv_s = v; wi_s = i;
            atomicMax(&assigned[i], g);
        }
        __syncthreads();
        float wv = wv_s; int wi = wi_s;
        for (int i = tid; i < cnt; i += 256) {
            if (lcost[i] == wv && lidx[i] == wi) lcost[i] = 3.4e38f;  // unique per anchor
        }
        __syncthreads();
    }
}

// K3: labels/boxes for all anchors; score element only for positives (zeros via memsetAsync).
__global__ __launch_bounds__(256) void k3_final(const float* __restrict__ pred_boxes,
                                                const int* __restrict__ gt_labels,
                                                const float* __restrict__ gt_boxes,
                                                const int* __restrict__ assigned,
                                                float* __restrict__ out) {
    int a = blockIdx.x * 256 + threadIdx.x;
    if (a >= A_N) return;
    int g = assigned[a];
    float* lbl_out = out;
    float* box_out = out + A_N;
    float* sc_out = out + 5 * A_N;
    if (g >= 0) {
        int lbl = gt_labels[g];
        lbl_out[a] = (float)lbl;
        float4 gb = *(const float4*)(gt_boxes + 4 * g);
        *(float4*)(box_out + 4 * a) = gb;
        float4 pb = *(const float4*)(pred_boxes + 4 * a);
        float ltx = fmaxf(pb.x, gb.x), lty = fmaxf(pb.y, gb.y);
        float rbx = fminf(pb.z, gb.z), rby = fminf(pb.w, gb.w);
        float wx = fmaxf(rbx - ltx, 0.f), wy = fmaxf(rby - lty, 0.f);
        float ov = wx * wy;
        float area_p = (pb.z - pb.x) * (pb.w - pb.y);
        float area_g = (gb.z - gb.x) * (gb.w - gb.y);
        float iou = ov / (area_p + area_g - ov + 1e-6f);
        sc_out[(size_t)a * 81 + lbl] = iou;
    } else {
        lbl_out[a] = 80.0f;
        float4 z; z.x = 0.f; z.y = 0.f; z.z = 0.f; z.w = 0.f;
        *(float4*)(box_out + 4 * a) = z;
    }
}

extern "C" void kernel_launch(void* const* d_in, const int* in_sizes, int n_in,
                              void* d_out, int out_size, void* d_ws, size_t ws_size,
                              hipStream_t stream) {
    (void)in_sizes; (void)n_in; (void)out_size; (void)ws_size;
    const float* pred_scores = (const float*)d_in[0];
    const float* pred_bboxes = (const float*)d_in[1];
    const float* anchor_pts  = (const float*)d_in[2];
    const int*   gt_labels   = (const int*)d_in[3];
    const float* gt_boxes    = (const float*)d_in[4];
    float* out = (float*)d_out;

    char* ws = (char*)d_ws;
    size_t off = 0;
    float*  sT        = (float*)(ws + off);  off += (size_t)C_N * A_N * 4;   // 10.75 MB
    float4* sbox      = (float4*)(ws + off); off += (size_t)A_N * 16;
    float2* sxy       = (float2*)(ws + off); off += (size_t)A_N * 8;
    float*  total_neg = (float*)(ws + off);  off += (size_t)A_N * 4;
    float*  stn       = (float*)(ws + off);  off += (size_t)A_N * 4;
    int*    assigned  = (int*)(ws + off);    off += (size_t)A_N * 4;
    int*    sidx      = (int*)(ws + off);    off += (size_t)A_N * 4;
    int*    cellcnt   = (int*)(ws + off);    off += (size_t)NC * 4;
    int*    fill      = (int*)(ws + off);    off += (size_t)NC * 4;
    int*    offsets   = (int*)(ws + off);    off += (size_t)(NC + 1) * 4;

    hipMemsetAsync(cellcnt, 0, (size_t)NC * 8, stream);                     // cellcnt + fill
    hipMemsetAsync(out + 5 * (size_t)A_N, 0, (size_t)A_N * 81 * 4, stream); // scores = 0
    k1_prep<<<(A_N + 127) / 128, 256, 0, stream>>>(pred_scores, anchor_pts, total_neg,
                                                   sT, assigned, cellcnt);
    k0_scan<<<1, 256, 0, stream>>>(cellcnt, offsets);
    k0_scatter<<<(A_N + 255) / 256, 256, 0, stream>>>(anchor_pts, pred_bboxes, total_neg,
                                                      offsets, fill, sxy, sbox, stn, sidx);
    k2_assign<<<G_N, 256, 0, stream>>>(sxy, sbox, stn, sidx, sT, gt_labels, gt_boxes,
                                       offsets, assigned);
    k3_final<<<(A_N + 255) / 256, 256, 0, stream>>>(pred_bboxes, gt_labels, gt_boxes,
                                                    assigned, out);
}

// Round 6
// 122.042 us; speedup vs baseline: 1.7464x; 1.3221x over previous
//
#include <hip/hip_runtime.h>
#include <cstdint>
#include <cstddef>

#define A_N 33600
#define G_N 256
#define C_N 80
#define TOPK 10
#define CAP 2048
#define GW 40           // 40x40 grid of 32-px cells
#define NC (GW * GW)    // 1600 cells

// Inputs: float32 (pred_scores, pred_bboxes, anchor_points, gt_bboxes), int32 gt_labels.
// Output (float32 flat): labels[A] | bboxes[A*4] | scores[A*81].

// K1: total_neg[a] = sum_c softplus(scores[a,c]); 4 threads/anchor, float4 loads,
// f32 terms accumulated in f64 (ordering-only quantity; ~1e-11 perturbation vs ref is
// far below selection gaps). Fused: assigned[a]=-1 and anchor-cell histogram.
__global__ __launch_bounds__(256) void k1_prep(const float* __restrict__ scores,
                                               const float* __restrict__ anchor_pts,
                                               float* __restrict__ total_neg,
                                               int* __restrict__ assigned,
                                               int* __restrict__ cellcnt) {
    const int tid = threadIdx.x;
    const int a = blockIdx.x * 64 + (tid >> 2);   // grid = A_N/64 = 525 exactly
    const int k = tid & 3;
    const float4* __restrict__ p = (const float4*)(scores + (size_t)a * C_N + k * 20);
    double s = 0.0;
#pragma unroll
    for (int i = 0; i < 5; ++i) {
        float4 v = p[i];
        s += (double)(fmaxf(v.x, 0.f) + log1pf(expf(-fabsf(v.x))));
        s += (double)(fmaxf(v.y, 0.f) + log1pf(expf(-fabsf(v.y))));
        s += (double)(fmaxf(v.z, 0.f) + log1pf(expf(-fabsf(v.z))));
        s += (double)(fmaxf(v.w, 0.f) + log1pf(expf(-fabsf(v.w))));
    }
    // combine the 4 partials (lanes 4m..4m+3 are in the same wave)
    s += __shfl_xor(s, 1);
    s += __shfl_xor(s, 2);
    if (k == 0) {
        total_neg[a] = (float)s;
        assigned[a] = -1;
        float2 ap = *(const float2*)(anchor_pts + 2 * a);
        int cx = min(GW - 1, (int)(ap.x * (1.f / 32.f)));  // ap in [0,1280]
        int cy = min(GW - 1, (int)(ap.y * (1.f / 32.f)));
        atomicAdd(&cellcnt[cy * GW + cx], 1);
    }
}

// K0b: exclusive scan of cellcnt[1600] -> offsets[1601]; single block.
__global__ __launch_bounds__(256) void k0_scan(const int* __restrict__ cellcnt,
                                               int* __restrict__ offsets) {
    __shared__ int part[256];
    const int tid = threadIdx.x;
    const int CH = 7;  // 256*7 = 1792 >= 1601
    int base = tid * CH;
    int loc[CH];
    int s = 0;
    for (int i = 0; i < CH; ++i) {
        int c = base + i;
        int v = (c < NC) ? cellcnt[c] : 0;
        loc[i] = s;
        s += v;
    }
    part[tid] = s;
    __syncthreads();
    for (int off = 1; off < 256; off <<= 1) {
        int v = (tid >= off) ? part[tid - off] : 0;
        __syncthreads();
        part[tid] += v;
        __syncthreads();
    }
    int pre = (tid == 0) ? 0 : part[tid - 1];
    for (int i = 0; i < CH; ++i) {
        int c = base + i;
        if (c <= NC) offsets[c] = pre + loc[i];
    }
}

// K0c: counting-sort scatter of per-anchor data (xy, box, total_neg, orig idx).
__global__ __launch_bounds__(256) void k0_scatter(const float* __restrict__ anchor_pts,
                                                  const float* __restrict__ pred_boxes,
                                                  const float* __restrict__ total_neg,
                                                  const int* __restrict__ offsets,
                                                  int* __restrict__ fill,
                                                  float2* __restrict__ sxy,
                                                  float4* __restrict__ sbox,
                                                  float* __restrict__ stn,
                                                  int* __restrict__ sidx) {
    int a = blockIdx.x * 256 + threadIdx.x;
    if (a >= A_N) return;
    float2 ap = *(const float2*)(anchor_pts + 2 * a);
    int cx = min(GW - 1, (int)(ap.x * (1.f / 32.f)));
    int cy = min(GW - 1, (int)(ap.y * (1.f / 32.f)));
    int cell = cy * GW + cx;
    int pos = offsets[cell] + atomicAdd(&fill[cell], 1);
    sxy[pos] = ap;
    sbox[pos] = *(const float4*)(pred_boxes + 4 * a);
    stn[pos] = total_neg[a];
    sidx[pos] = a;
}

// K2: one block per GT. Scan only this GT's cell rows (contiguous ranges).
// Winner keyed on (exact f32 cost, orig anchor idx) -> order-independent, matches np top_k.
// Label score gathered directly from scores[a*80+lbl] (no transpose needed).
__global__ __launch_bounds__(256) void k2_assign(const float2* __restrict__ sxy,
                                                 const float4* __restrict__ sbox,
                                                 const float* __restrict__ stn,
                                                 const int* __restrict__ sidx,
                                                 const float* __restrict__ scores,
                                                 const int* __restrict__ gt_labels,
                                                 const float* __restrict__ gt_boxes,
                                                 const int* __restrict__ offsets,
                                                 int* __restrict__ assigned) {
    __shared__ float lcost[CAP];
    __shared__ int   lidx[CAP];
    __shared__ float rv[4];
    __shared__ int   ri[4];
    __shared__ float wv_s;
    __shared__ int   wi_s;
    __shared__ int lcnt, lpos;
    const int g = blockIdx.x;
    const int tid = threadIdx.x;
    if (tid == 0) { lcnt = 0; lpos = 0; }
    __syncthreads();

    const float4 gb = *(const float4*)(gt_boxes + 4 * g);
    const int lbl = gt_labels[g];
    const float area_g = (gb.z - gb.x) * (gb.w - gb.y);

    int cx0 = max(0, (int)floorf(gb.x * (1.f / 32.f)));
    int cx1 = min(GW - 1, (int)floorf(gb.z * (1.f / 32.f)));
    int cy0 = max(0, (int)floorf(gb.y * (1.f / 32.f)));
    int cy1 = min(GW - 1, (int)floorf(gb.w * (1.f / 32.f)));

    for (int cy = cy0; cy <= cy1; ++cy) {
        int lo = offsets[cy * GW + cx0];
        int hi = offsets[cy * GW + cx1 + 1];
        for (int i = lo + tid; i < hi; i += 256) {
            float2 ap = sxy[i];
            if (ap.x >= gb.x && ap.x <= gb.z && ap.y >= gb.y && ap.y <= gb.w) {
                float4 pb = sbox[i];
                float ltx = fmaxf(pb.x, gb.x), lty = fmaxf(pb.y, gb.y);
                float rbx = fminf(pb.z, gb.z), rby = fminf(pb.w, gb.w);
                float wx = fmaxf(rbx - ltx, 0.f), wy = fmaxf(rby - lty, 0.f);
                float ov = wx * wy;
                float area_p = (pb.z - pb.x) * (pb.w - pb.y);
                float iou = ov / (area_p + area_g - ov + 1e-6f);
                int oa = sidx[i];
                float cost = (stn[i] - scores[(size_t)oa * C_N + lbl])
                             + 3.0f * (-logf(fmaxf(iou, 1e-7f)));
                int k = atomicAdd(&lcnt, 1);
                if (k < CAP) { lcost[k] = cost; lidx[k] = oa; }
                if (ov > 0.f) atomicAdd(&lpos, 1);
            }
        }
    }
    __syncthreads();
    const int cnt = min(lcnt, CAP);
    const int dynk = min(max(lpos, 1), TOPK);

    if (cnt == 0) {
        // all-outside row: f32 cost+1e10 collapses (|cost|<512=ulp/2) -> ref top_k -> anchor 0
        if (tid == 0) atomicMax(&assigned[0], g);
        return;
    }
    for (int r = 0; r < dynk; ++r) {
        float bv = 3.4e38f; int bi = 0x7FFFFFFF;
        for (int i = tid; i < cnt; i += 256) {
            float v = lcost[i]; int ai = lidx[i];
            if (v < bv || (v == bv && ai < bi)) { bv = v; bi = ai; }
        }
        for (int off = 32; off; off >>= 1) {
            float vv = __shfl_down(bv, off);
            int ii = __shfl_down(bi, off);
            if (vv < bv || (vv == bv && ii < bi)) { bv = vv; bi = ii; }
        }
        if ((tid & 63) == 0) { rv[tid >> 6] = bv; ri[tid >> 6] = bi; }
        __syncthreads();
        if (tid == 0) {
            float v = rv[0]; int i = ri[0];
            for (int w = 1; w < 4; ++w)
                if (rv[w] < v || (rv[w] == v && ri[w] < i)) { v = rv[w]; i = ri[w]; }
            wv_s = v; wi_s = i;
            atomicMax(&assigned[i], g);
        }
        __syncthreads();
        float wv = wv_s; int wi = wi_s;
        for (int i = tid; i < cnt; i += 256) {
            if (lcost[i] == wv && lidx[i] == wi) lcost[i] = 3.4e38f;  // unique per anchor
        }
        __syncthreads();
    }
}

// K3: zero score rows (coalesced, block-local), then labels/boxes/scatter-score.
__global__ __launch_bounds__(256) void k3_final(const float* __restrict__ pred_boxes,
                                                const int* __restrict__ gt_labels,
                                                const float* __restrict__ gt_boxes,
                                                const int* __restrict__ assigned,
                                                float* __restrict__ out) {
    const int a0 = blockIdx.x * 256;
    const int tid = threadIdx.x;
    const int hi = min(a0 + 256, A_N);
    float* __restrict__ sc_out = out + 5 * A_N;
    const int n = (hi - a0) * 81;
    for (int i = tid; i < n; i += 256) sc_out[(size_t)a0 * 81 + i] = 0.f;
    __syncthreads();
    int a = a0 + tid;
    if (a >= A_N) return;
    int g = assigned[a];
    float* lbl_out = out;
    float* box_out = out + A_N;
    if (g >= 0) {
        int lbl = gt_labels[g];
        lbl_out[a] = (float)lbl;
        float4 gb = *(const float4*)(gt_boxes + 4 * g);
        *(float4*)(box_out + 4 * a) = gb;
        float4 pb = *(const float4*)(pred_boxes + 4 * a);
        float ltx = fmaxf(pb.x, gb.x), lty = fmaxf(pb.y, gb.y);
        float rbx = fminf(pb.z, gb.z), rby = fminf(pb.w, gb.w);
        float wx = fmaxf(rbx - ltx, 0.f), wy = fmaxf(rby - lty, 0.f);
        float ov = wx * wy;
        float area_p = (pb.z - pb.x) * (pb.w - pb.y);
        float area_g = (gb.z - gb.x) * (gb.w - gb.y);
        float iou = ov / (area_p + area_g - ov + 1e-6f);
        sc_out[(size_t)a * 81 + lbl] = iou;
    } else {
        lbl_out[a] = 80.0f;
        float4 z; z.x = 0.f; z.y = 0.f; z.z = 0.f; z.w = 0.f;
        *(float4*)(box_out + 4 * a) = z;
    }
}

extern "C" void kernel_launch(void* const* d_in, const int* in_sizes, int n_in,
                              void* d_out, int out_size, void* d_ws, size_t ws_size,
                              hipStream_t stream) {
    (void)in_sizes; (void)n_in; (void)out_size; (void)ws_size;
    const float* pred_scores = (const float*)d_in[0];
    const float* pred_bboxes = (const float*)d_in[1];
    const float* anchor_pts  = (const float*)d_in[2];
    const int*   gt_labels   = (const int*)d_in[3];
    const float* gt_boxes    = (const float*)d_in[4];
    float* out = (float*)d_out;

    char* ws = (char*)d_ws;
    size_t off = 0;
    float4* sbox      = (float4*)(ws + off); off += (size_t)A_N * 16;
    float2* sxy       = (float2*)(ws + off); off += (size_t)A_N * 8;
    float*  total_neg = (float*)(ws + off);  off += (size_t)A_N * 4;
    float*  stn       = (float*)(ws + off);  off += (size_t)A_N * 4;
    int*    assigned  = (int*)(ws + off);    off += (size_t)A_N * 4;
    int*    sidx      = (int*)(ws + off);    off += (size_t)A_N * 4;
    int*    cellcnt   = (int*)(ws + off);    off += (size_t)NC * 4;
    int*    fill      = (int*)(ws + off);    off += (size_t)NC * 4;
    int*    offsets   = (int*)(ws + off);    off += (size_t)(NC + 1) * 4;

    hipMemsetAsync(cellcnt, 0, (size_t)NC * 8, stream);  // cellcnt + fill (adjacent)
    k1_prep<<<A_N / 64, 256, 0, stream>>>(pred_scores, anchor_pts, total_neg,
                                          assigned, cellcnt);
    k0_scan<<<1, 256, 0, stream>>>(cellcnt, offsets);
    k0_scatter<<<(A_N + 255) / 256, 256, 0, stream>>>(anchor_pts, pred_bboxes, total_neg,
                                                      offsets, fill, sxy, sbox, stn, sidx);
    k2_assign<<<G_N, 256, 0, stream>>>(sxy, sbox, stn, sidx, pred_scores, gt_labels,
                                       gt_boxes, offsets, assigned);
    k3_final<<<(A_N + 255) / 256, 256, 0, stream>>>(pred_bboxes, gt_labels, gt_boxes,
                                                    assigned, out);
}